// Round 2
// baseline (837.461 us; speedup 1.0000x reference)
//
#include <hip/hip_runtime.h>

typedef unsigned int uint;
typedef unsigned short ushort_t;
typedef ushort_t ushort8 __attribute__((ext_vector_type(8)));
typedef short short8 __attribute__((ext_vector_type(8)));
typedef float floatx4 __attribute__((ext_vector_type(4)));

#define WSQ 25165824L   // elements per q/k/v tensor: 256*12*256*32
#define NH  12
#define NT  256
#define HD  32

__device__ __forceinline__ float bf2f(ushort_t u) {
    uint x = ((uint)u) << 16;
    return __builtin_bit_cast(float, x);
}
__device__ __forceinline__ ushort_t f2bf(float f) {
    uint u = __builtin_bit_cast(uint, f);
    uint lsb = (u >> 16) & 1u;
    return (ushort_t)((u + 0x7FFFu + lsb) >> 16);
}
// dual-dtype input loads: f==1 -> input is float32, f==0 -> bf16
__device__ __forceinline__ float ld1(const void* p, long i, int f) {
    return f ? ((const float*)p)[i] : bf2f(((const ushort_t*)p)[i]);
}
__device__ __forceinline__ ushort8 ld8(const void* p, long i, int f) {
    ushort8 o;
    if (f) {
        const float* fp = (const float*)p + i;
#pragma unroll
        for (int j = 0; j < 8; ++j) o[j] = f2bf(fp[j]);
    } else {
        o = *(const ushort8*)((const ushort_t*)p + i);
    }
    return o;
}

// ---------------- dtype detection: 1 wave ----------------
__global__ void detect_kernel(const ushort_t* __restrict__ x, int* __restrict__ flag) {
    int t = threadIdx.x;                 // 64 threads
    uint u = x[2 * t];                   // low half if f32, element 2t if bf16
    int e = (u >> 7) & 0xFF;
    int weird = (e > 147 || e < 107) ? 1 : 0;   // |exp-127| > 20
    unsigned long long b = __ballot(weird);
    if (t == 0) *flag = (__popcll(b) > 19) ? 1 : 0;   // >30% weird -> f32
}

// ---------------- CPB MLP: 2 -> 512 -> 12 ----------------
__global__ __launch_bounds__(512) void cpb_kernel(
    const void* __restrict__ tab, const void* __restrict__ w1,
    const void* __restrict__ b1, const void* __restrict__ w2,
    const int* __restrict__ fl, float* __restrict__ bt)
{
    __shared__ float hid[512];
    const int f = *fl;
    int p = blockIdx.x, j = threadIdx.x;
    float c0 = ld1(tab, p * 2 + 0, f);
    float c1 = ld1(tab, p * 2 + 1, f);
    float v = ld1(w1, j * 2 + 0, f) * c0 + ld1(w1, j * 2 + 1, f) * c1 + ld1(b1, j, f);
    hid[j] = fmaxf(v, 0.0f);
    __syncthreads();
    if (j < NH) {
        float s = 0.0f;
        for (int i = 0; i < 512; ++i) s += hid[i] * ld1(w2, (long)j * 512 + i, f);
        bt[p * NH + j] = s;
    }
}

// ---------------- rpb gather + 16*sigmoid ----------------
__global__ __launch_bounds__(256) void rpb_kernel(
    const int* __restrict__ rpi, const float* __restrict__ bt,
    float* __restrict__ rpb)
{
    int idx = blockIdx.x * 256 + threadIdx.x;      // 12*65536 total
    int h = idx >> 16, ij = idx & 65535;
    float x = bt[rpi[ij] * NH + h];
    rpb[idx] = 16.0f / (1.0f + __expf(-x));
}

// ---------------- GEMM C = A[M,384] @ W[N,384]^T + bias ----------------
// MODE 0: qkv projection: A = x (dual dtype), scatter-store bf16 [which][B,H,N,32]
// MODE 1: out projection: A = attn overlay in qkv q-region (bf16), store dual to d_out
template <int MODE>
__global__ __launch_bounds__(256) void gemm_bt(
    const void* __restrict__ A, const void* __restrict__ Bw,
    const void* __restrict__ bias0, const void* __restrict__ bias2,
    void* __restrict__ Cout, const int* __restrict__ fl)
{
    const int K = 384;
    __shared__ ushort_t As[128 * 72];
    __shared__ ushort_t Bs[128 * 72];
    const int f = *fl;
    const int tid = threadIdx.x;
    const int w = tid >> 6, lane = tid & 63, l15 = lane & 15, quad = lane >> 4;
    const int m0 = blockIdx.x * 128, n0 = blockIdx.y * 128;
    const int rw = (w >> 1) * 64, cw = (w & 1) * 64;
    const int lr = tid >> 3, lc = (tid & 7) * 8;

    floatx4 acc[4][4] = {};

    for (int kt = 0; kt < K; kt += 64) {
        for (int i = 0; i < 4; ++i) {
            int r = lr + i * 32;
            if (MODE == 0) {
                *(ushort8*)&As[r * 72 + lc] = ld8(A, (long)(m0 + r) * K + kt + lc, f);
            } else {
                // A is attention-out overlay: row m=(b*256+n), col c=(h*32+d) at
                // qkv[((m>>8)*12 + (c>>5))*8192 + (m&255)*32 + (c&31)]
                int m = m0 + r, kc = kt + lc;
                long ad = ((long)(m >> 8) * 12 + (kc >> 5)) * 8192 + (m & 255) * 32 + (kc & 31);
                *(ushort8*)&As[r * 72 + lc] = *(const ushort8*)((const ushort_t*)A + ad);
            }
            *(ushort8*)&Bs[r * 72 + lc] = ld8(Bw, (long)(n0 + r) * K + kt + lc, f);
        }
        __syncthreads();
        for (int ks = 0; ks < 64; ks += 32) {
            short8 af[4], bfr[4];
            for (int mt = 0; mt < 4; ++mt)
                af[mt] = *(short8*)&As[(rw + mt * 16 + l15) * 72 + ks + quad * 8];
            for (int nt = 0; nt < 4; ++nt)
                bfr[nt] = *(short8*)&Bs[(cw + nt * 16 + l15) * 72 + ks + quad * 8];
            for (int mt = 0; mt < 4; ++mt)
                for (int nt = 0; nt < 4; ++nt)
                    acc[mt][nt] = __builtin_amdgcn_mfma_f32_16x16x32_bf16(
                        af[mt], bfr[nt], acc[mt][nt], 0, 0, 0);
        }
        __syncthreads();
    }

    for (int mt = 0; mt < 4; ++mt) {
        for (int nt = 0; nt < 4; ++nt) {
            int c = n0 + cw + nt * 16 + l15;
            if (MODE == 0) {
                int which = c / 384, cc = c % 384;
                float bias = (which == 0) ? ld1(bias0, cc, f)
                           : (which == 2) ? ld1(bias2, cc, f) : 0.0f;
                int hh = cc >> 5, dd = cc & 31;
                for (int r = 0; r < 4; ++r) {
                    int m = m0 + rw + mt * 16 + quad * 4 + r;
                    int b = m >> 8, ntok = m & 255;
                    long dst = (long)which * WSQ +
                               (((long)(b * NH + hh) * NT + ntok) * HD + dd);
                    ((ushort_t*)Cout)[dst] = f2bf(acc[mt][nt][r] + bias);
                }
            } else {
                float bias = ld1(bias0, c, f);
                for (int r = 0; r < 4; ++r) {
                    int m = m0 + rw + mt * 16 + quad * 4 + r;
                    float v = acc[mt][nt][r] + bias;
                    long o = (long)m * 384 + c;
                    if (f) ((float*)Cout)[o] = v;
                    else   ((ushort_t*)Cout)[o] = f2bf(v);
                }
            }
        }
    }
}

// ---------------- fused window attention: one block per (b,h), 128 thr ----------------
// Output overlays the q region: out(b,n,h,d) -> qkv[(b*NH+h)*NT*HD + n*HD + d]
__global__ __launch_bounds__(128) void attn_kernel(
    ushort_t* __restrict__ qkv, const void* __restrict__ ls,
    const float* __restrict__ rpb, const int* __restrict__ fl)
{
    __shared__ ushort_t ks[256 * 40];     // normalized K rows, stride 40
    __shared__ ushort_t vts[32 * 264];    // V^T [d][key], stride 264
    __shared__ ushort_t ps[2 * 16 * 264]; // per-wave P strip [16][256+pad]

    const int f = *fl;
    const int bh = blockIdx.x;
    const int b = bh / NH, h = bh % NH;
    ushort_t* qp = qkv + (long)bh * NT * HD;
    const ushort_t* kp = qp + WSQ;
    const ushort_t* vp = qp + 2 * WSQ;
    const int tid = threadIdx.x;
    const float scale = __expf(fminf(ld1(ls, h, f), 4.6051702f)); // log(100)

    // ---- stage K (L2-normalized) and V^T ----
    for (int t = tid; t < 256; t += 128) {
        ushort8 kv[4];
        for (int i = 0; i < 4; ++i) kv[i] = *(const ushort8*)&kp[t * HD + i * 8];
        float fv[32]; float ss = 0.0f;
        for (int i = 0; i < 4; ++i)
            for (int j = 0; j < 8; ++j) {
                float v = bf2f(kv[i][j]); fv[i * 8 + j] = v; ss += v * v;
            }
        float rn = 1.0f / fmaxf(sqrtf(ss), 1e-12f);
        for (int i = 0; i < 4; ++i) {
            ushort8 o;
            for (int j = 0; j < 8; ++j) o[j] = f2bf(fv[i * 8 + j] * rn);
            *(ushort8*)&ks[t * 40 + i * 8] = o;
        }
        ushort8 vv[4];
        for (int i = 0; i < 4; ++i) vv[i] = *(const ushort8*)&vp[t * HD + i * 8];
        for (int i = 0; i < 4; ++i)
            for (int j = 0; j < 8; ++j) vts[(i * 8 + j) * 264 + t] = vv[i][j];
    }
    __syncthreads();

    const int w = tid >> 6, lane = tid & 63, l15 = lane & 15, quad = lane >> 4;
    ushort_t* psw = &ps[w * 16 * 264];

    for (int c = 0; c < 8; ++c) {
        const int mloc = w * 128 + c * 16;

        // q fragment (read BEFORE overlay write of same rows below)
        ushort8 qv = *(const ushort8*)&qp[(mloc + l15) * HD + quad * 8];
        float qf[8]; float ss = 0.0f;
        for (int j = 0; j < 8; ++j) { qf[j] = bf2f(qv[j]); ss += qf[j] * qf[j]; }
        ss += __shfl_xor(ss, 16, 64);
        ss += __shfl_xor(ss, 32, 64);
        float rn = 1.0f / fmaxf(sqrtf(ss), 1e-12f);
        short8 aq;
        for (int j = 0; j < 8; ++j) aq[j] = (short)f2bf(qf[j] * rn);

        // S strip: 16 rows x 256 cols in 64 acc VGPRs
        floatx4 accS[16];
        for (int t = 0; t < 16; ++t) {
            short8 bk = *(short8*)&ks[(t * 16 + l15) * 40 + quad * 8];
            floatx4 z = {};
            accS[t] = __builtin_amdgcn_mfma_f32_16x16x32_bf16(aq, bk, z, 0, 0, 0);
        }

        // scale + rpb + exact row softmax (fp32)
        const float* rpbp = rpb + ((long)(h * NT + mloc + quad * 4)) * NT + l15;
        float rmax[4] = {-1e30f, -1e30f, -1e30f, -1e30f};
        for (int t = 0; t < 16; ++t)
            for (int r = 0; r < 4; ++r) {
                float v = accS[t][r] * scale + rpbp[r * NT + t * 16];
                accS[t][r] = v;
                rmax[r] = fmaxf(rmax[r], v);
            }
        for (int r = 0; r < 4; ++r) {
            rmax[r] = fmaxf(rmax[r], __shfl_xor(rmax[r], 1, 64));
            rmax[r] = fmaxf(rmax[r], __shfl_xor(rmax[r], 2, 64));
            rmax[r] = fmaxf(rmax[r], __shfl_xor(rmax[r], 4, 64));
            rmax[r] = fmaxf(rmax[r], __shfl_xor(rmax[r], 8, 64));
        }
        float rsum[4] = {0, 0, 0, 0};
        for (int t = 0; t < 16; ++t)
            for (int r = 0; r < 4; ++r) {
                float p = __expf(accS[t][r] - rmax[r]);
                rsum[r] += p;
                psw[(quad * 4 + r) * 264 + t * 16 + l15] = f2bf(p);
            }
        for (int r = 0; r < 4; ++r) {
            rsum[r] += __shfl_xor(rsum[r], 1, 64);
            rsum[r] += __shfl_xor(rsum[r], 2, 64);
            rsum[r] += __shfl_xor(rsum[r], 4, 64);
            rsum[r] += __shfl_xor(rsum[r], 8, 64);
        }

        // PV: P[16,256] @ V[256,32] via V^T fragments
        floatx4 accO[2] = {};
        for (int kk = 0; kk < 8; ++kk) {
            short8 pf = *(short8*)&psw[l15 * 264 + kk * 32 + quad * 8];
            for (int tn = 0; tn < 2; ++tn) {
                short8 vf = *(short8*)&vts[(tn * 16 + l15) * 264 + kk * 32 + quad * 8];
                accO[tn] = __builtin_amdgcn_mfma_f32_16x16x32_bf16(pf, vf, accO[tn], 0, 0, 0);
            }
        }

        // epilogue: divide by rowsum, overlay-store into q slice (bf16)
        for (int tn = 0; tn < 2; ++tn)
            for (int r = 0; r < 4; ++r) {
                int n = mloc + quad * 4 + r;
                qp[n * HD + tn * 16 + l15] = f2bf(accO[tn][r] / rsum[r]);
            }
    }
}

extern "C" void kernel_launch(void* const* d_in, const int* in_sizes, int n_in,
                              void* d_out, int out_size, void* d_ws, size_t ws_size,
                              hipStream_t stream)
{
    const void* x      = d_in[0];
    const void* qkv_w  = d_in[1];
    const void* q_bias = d_in[2];
    const void* v_bias = d_in[3];
    const void* lscale = d_in[4];
    const void* cpb_w1 = d_in[5];
    const void* cpb_b1 = d_in[6];
    const void* cpb_w2 = d_in[7];
    const void* proj_w = d_in[8];
    const void* proj_b = d_in[9];
    const void* rct    = d_in[10];
    const int*  rpi    = (const int*)d_in[11];

    char* ws = (char*)d_ws;
    ushort_t* qkv_ws = (ushort_t*)ws;                          // 3*WSQ bf16 = 150,994,944 B
    float*    bt     = (float*)(ws + 150994944L);              // 961*12 f32 (reserve 64K)
    float*    rpb    = (float*)(ws + 150994944L + 65536L);     // 12*65536 f32
    int*      flag   = (int*)(ws + 150994944L + 65536L + 3145728L);

    detect_kernel<<<1, 64, 0, stream>>>((const ushort_t*)x, flag);
    cpb_kernel<<<961, 512, 0, stream>>>(rct, cpb_w1, cpb_b1, cpb_w2, flag, bt);
    rpb_kernel<<<3072, 256, 0, stream>>>(rpi, bt, rpb);
    gemm_bt<0><<<dim3(512, 9), 256, 0, stream>>>(x, qkv_w, q_bias, v_bias, qkv_ws, flag);
    attn_kernel<<<3072, 128, 0, stream>>>(qkv_ws, lscale, rpb, flag);
    gemm_bt<1><<<dim3(512, 3), 256, 0, stream>>>(qkv_ws, proj_w, proj_b, nullptr, d_out, flag);
}

// Round 3
// 537.659 us; speedup vs baseline: 1.5576x; 1.5576x over previous
//
#include <hip/hip_runtime.h>

typedef unsigned int uint;
typedef unsigned short ushort_t;
typedef ushort_t ushort8 __attribute__((ext_vector_type(8)));
typedef ushort_t ushort4v __attribute__((ext_vector_type(4)));
typedef short short8 __attribute__((ext_vector_type(8)));
typedef float floatx4 __attribute__((ext_vector_type(4)));

#define WSQ 25165824L   // elements per q/k/v tensor: 256*12*256*32
#define NH  12
#define NT  256
#define HD  32

__device__ __forceinline__ float bf2f(ushort_t u) {
    uint x = ((uint)u) << 16;
    return __builtin_bit_cast(float, x);
}
__device__ __forceinline__ ushort_t f2bf(float f) {
    uint u = __builtin_bit_cast(uint, f);
    uint lsb = (u >> 16) & 1u;
    return (ushort_t)((u + 0x7FFFu + lsb) >> 16);
}
__device__ __forceinline__ float ld1(const void* p, long i, int f) {
    return f ? ((const float*)p)[i] : bf2f(((const ushort_t*)p)[i]);
}

// ---------------- dtype detection: 1 wave ----------------
__global__ void detect_kernel(const ushort_t* __restrict__ x, int* __restrict__ flag) {
    int t = threadIdx.x;                 // 64 threads
    uint u = x[2 * t];                   // low half if f32, element 2t if bf16
    int e = (u >> 7) & 0xFF;
    int weird = (e > 147 || e < 107) ? 1 : 0;   // |exp-127| > 20
    unsigned long long b = __ballot(weird);
    if (t == 0) *flag = (__popcll(b) > 19) ? 1 : 0;   // >30% weird -> f32
}

// ---------------- convert to bf16 (or copy) ----------------
__global__ __launch_bounds__(256) void cvt_kernel(
    const void* __restrict__ src, ushort_t* __restrict__ dst,
    const int* __restrict__ fl, long n8)
{
    long i = (long)blockIdx.x * 256 + threadIdx.x;
    if (i >= n8) return;
    if (*fl) {
        const floatx4* s = (const floatx4*)((const float*)src + i * 8);
        floatx4 a = s[0], b = s[1];
        ushort8 o;
        for (int j = 0; j < 4; ++j) { o[j] = f2bf(a[j]); o[4 + j] = f2bf(b[j]); }
        *(ushort8*)(dst + i * 8) = o;
    } else {
        *(ushort8*)(dst + i * 8) = *(const ushort8*)((const ushort_t*)src + i * 8);
    }
}

// ---------------- CPB MLP: 2 -> 512 -> 12 ----------------
__global__ __launch_bounds__(512) void cpb_kernel(
    const void* __restrict__ tab, const void* __restrict__ w1,
    const void* __restrict__ b1, const void* __restrict__ w2,
    const int* __restrict__ fl, float* __restrict__ bt)
{
    __shared__ float hid[512];
    const int f = *fl;
    int p = blockIdx.x, j = threadIdx.x;
    float c0 = ld1(tab, p * 2 + 0, f);
    float c1 = ld1(tab, p * 2 + 1, f);
    float v = ld1(w1, j * 2 + 0, f) * c0 + ld1(w1, j * 2 + 1, f) * c1 + ld1(b1, j, f);
    hid[j] = fmaxf(v, 0.0f);
    __syncthreads();
    if (j < NH) {
        float s = 0.0f;
        for (int i = 0; i < 512; ++i) s += hid[i] * ld1(w2, (long)j * 512 + i, f);
        bt[p * NH + j] = s;
    }
}

// ---------------- rpb gather + 16*sigmoid ----------------
__global__ __launch_bounds__(256) void rpb_kernel(
    const int* __restrict__ rpi, const float* __restrict__ bt,
    float* __restrict__ rpb)
{
    int idx = blockIdx.x * 256 + threadIdx.x;      // 12*65536 total
    int h = idx >> 16, ij = idx & 65535;
    float x = bt[rpi[ij] * NH + h];
    rpb[idx] = 16.0f / (1.0f + __expf(-x));
}

// ---------------- GEMM C = A[M,384] @ W[N,384]^T + bias (all bf16 in) ----------------
// MODE 0: qkv projection: A = xb, scatter-store bf16 [which][B,H,N,32]
// MODE 1: out projection: A = attn overlay in qkv q-region, store dual to d_out
// grid: (n_blocks, m_blocks) -- N fastest for A-slab L2/L3 sharing
template <int MODE>
__global__ __launch_bounds__(256) void gemm_bt(
    const ushort_t* __restrict__ A, const ushort_t* __restrict__ Bw,
    const void* __restrict__ bias0, const void* __restrict__ bias2,
    void* __restrict__ Cout, const int* __restrict__ fl)
{
    const int K = 384;
    __shared__ ushort_t As[128 * 72];
    __shared__ ushort_t Bs[128 * 72];
    const int f = *fl;
    const int tid = threadIdx.x;
    const int w = tid >> 6, lane = tid & 63, l15 = lane & 15, quad = lane >> 4;
    const int m0 = blockIdx.y * 128, n0 = blockIdx.x * 128;
    const int rw = (w >> 1) * 64, cw = (w & 1) * 64;
    const int lr = tid >> 3, lc = (tid & 7) * 8;

    floatx4 acc[4][4] = {};
    ushort8 pa[4], pb[4];

    // prefetch K-tile 0
    for (int i = 0; i < 4; ++i) {
        int r = lr + i * 32;
        if (MODE == 0) {
            pa[i] = *(const ushort8*)&A[(long)(m0 + r) * K + lc];
        } else {
            int m = m0 + r, kc = lc;
            long ad = ((long)(m >> 8) * 12 + (kc >> 5)) * 8192 + (m & 255) * 32 + (kc & 31);
            pa[i] = *(const ushort8*)&A[ad];
        }
        pb[i] = *(const ushort8*)&Bw[(long)(n0 + r) * K + lc];
    }

    for (int kt = 0; kt < K; kt += 64) {
        for (int i = 0; i < 4; ++i) {
            int r = lr + i * 32;
            *(ushort8*)&As[r * 72 + lc] = pa[i];
            *(ushort8*)&Bs[r * 72 + lc] = pb[i];
        }
        __syncthreads();
        if (kt + 64 < K) {
            for (int i = 0; i < 4; ++i) {
                int r = lr + i * 32;
                if (MODE == 0) {
                    pa[i] = *(const ushort8*)&A[(long)(m0 + r) * K + kt + 64 + lc];
                } else {
                    int m = m0 + r, kc = kt + 64 + lc;
                    long ad = ((long)(m >> 8) * 12 + (kc >> 5)) * 8192 + (m & 255) * 32 + (kc & 31);
                    pa[i] = *(const ushort8*)&A[ad];
                }
                pb[i] = *(const ushort8*)&Bw[(long)(n0 + r) * K + kt + 64 + lc];
            }
        }
        for (int ks = 0; ks < 64; ks += 32) {
            short8 af[4], bfr[4];
            for (int mt = 0; mt < 4; ++mt)
                af[mt] = *(short8*)&As[(rw + mt * 16 + l15) * 72 + ks + quad * 8];
            for (int nt = 0; nt < 4; ++nt)
                bfr[nt] = *(short8*)&Bs[(cw + nt * 16 + l15) * 72 + ks + quad * 8];
            for (int mt = 0; mt < 4; ++mt)
                for (int nt = 0; nt < 4; ++nt)
                    acc[mt][nt] = __builtin_amdgcn_mfma_f32_16x16x32_bf16(
                        af[mt], bfr[nt], acc[mt][nt], 0, 0, 0);
        }
        __syncthreads();
    }

    for (int mt = 0; mt < 4; ++mt) {
        for (int nt = 0; nt < 4; ++nt) {
            int c = n0 + cw + nt * 16 + l15;
            if (MODE == 0) {
                int which = c / 384, cc = c % 384;
                float bias = (which == 0) ? ld1(bias0, cc, f)
                           : (which == 2) ? ld1(bias2, cc, f) : 0.0f;
                int hh = cc >> 5, dd = cc & 31;
                for (int r = 0; r < 4; ++r) {
                    int m = m0 + rw + mt * 16 + quad * 4 + r;
                    int b = m >> 8, ntok = m & 255;
                    long dst = (long)which * WSQ +
                               (((long)(b * NH + hh) * NT + ntok) * HD + dd);
                    ((ushort_t*)Cout)[dst] = f2bf(acc[mt][nt][r] + bias);
                }
            } else {
                float bias = ld1(bias0, c, f);
                for (int r = 0; r < 4; ++r) {
                    int m = m0 + rw + mt * 16 + quad * 4 + r;
                    float v = acc[mt][nt][r] + bias;
                    long o = (long)m * 384 + c;
                    if (f) ((float*)Cout)[o] = v;
                    else   ((ushort_t*)Cout)[o] = f2bf(v);
                }
            }
        }
    }
}

// ---------------- fused window attention: one block per (b,h), 128 thr ----------------
// Computes S^T per strip (token=lane col, key=reg row) -> float4 rpb loads,
// b64 P writes, scalar softmax state. Output overlays the q region.
__global__ __launch_bounds__(128) void attn_kernel(
    ushort_t* __restrict__ qkv, const void* __restrict__ ls,
    const float* __restrict__ rpb, const int* __restrict__ fl)
{
    __shared__ ushort_t ks[256 * 40];     // normalized K rows, stride 40
    __shared__ ushort_t vts[32 * 264];    // V^T [d][key], stride 264
    __shared__ ushort_t ps[2 * 16 * 264]; // per-wave P strip [16 tokens][256+pad keys]

    const int f = *fl;
    const int bh = blockIdx.x;
    const int b = bh / NH, h = bh % NH;
    ushort_t* qp = qkv + (long)bh * NT * HD;
    const ushort_t* kp = qp + WSQ;
    const ushort_t* vp = qp + 2 * WSQ;
    const int tid = threadIdx.x;
    const float scale = __expf(fminf(ld1(ls, h, f), 4.6051702f)); // log(100)

    // ---- stage K (L2-normalized) and V^T ----
    for (int t = tid; t < 256; t += 128) {
        ushort8 kv[4];
        for (int i = 0; i < 4; ++i) kv[i] = *(const ushort8*)&kp[t * HD + i * 8];
        float fv[32]; float ss = 0.0f;
        for (int i = 0; i < 4; ++i)
            for (int j = 0; j < 8; ++j) {
                float v = bf2f(kv[i][j]); fv[i * 8 + j] = v; ss += v * v;
            }
        float rn = 1.0f / fmaxf(sqrtf(ss), 1e-12f);
        for (int i = 0; i < 4; ++i) {
            ushort8 o;
            for (int j = 0; j < 8; ++j) o[j] = f2bf(fv[i * 8 + j] * rn);
            *(ushort8*)&ks[t * 40 + i * 8] = o;
        }
        ushort8 vv[4];
        for (int i = 0; i < 4; ++i) vv[i] = *(const ushort8*)&vp[t * HD + i * 8];
        for (int i = 0; i < 4; ++i)
            for (int j = 0; j < 8; ++j) vts[(i * 8 + j) * 264 + t] = vv[i][j];
    }
    __syncthreads();

    const int w = tid >> 6, lane = tid & 63, l15 = lane & 15, quad = lane >> 4;
    ushort_t* psw = &ps[w * 16 * 264];

    for (int c = 0; c < 8; ++c) {
        const int mloc = w * 128 + c * 16;

        // q fragment: lane holds q[mloc+l15][quad*8..+8]; normalize via shfl
        ushort8 qv = *(const ushort8*)&qp[(mloc + l15) * HD + quad * 8];
        float qf[8]; float ss = 0.0f;
        for (int j = 0; j < 8; ++j) { qf[j] = bf2f(qv[j]); ss += qf[j] * qf[j]; }
        ss += __shfl_xor(ss, 16, 64);
        ss += __shfl_xor(ss, 32, 64);
        float rn = 1.0f / fmaxf(sqrtf(ss), 1e-12f);
        short8 aq;
        for (int j = 0; j < 8; ++j) aq[j] = (short)f2bf(qf[j] * rn);

        // S^T strip: MFMA(A=k, B=q) -> D[key][token]; lane: token=l15, keys=t*16+quad*4+r
        floatx4 accS[16];
        for (int t = 0; t < 16; ++t) {
            short8 bk = *(short8*)&ks[(t * 16 + l15) * 40 + quad * 8];
            floatx4 z = {};
            accS[t] = __builtin_amdgcn_mfma_f32_16x16x32_bf16(bk, aq, z, 0, 0, 0);
        }

        // scale + rpb (float4) + exact softmax over keys (scalar state per lane)
        const float* rp = rpb + ((long)h * NT + mloc + l15) * NT;
        float rmax = -1e30f;
        for (int t = 0; t < 16; ++t) {
            floatx4 rb = *(const floatx4*)&rp[t * 16 + quad * 4];
            for (int r = 0; r < 4; ++r) {
                float v = accS[t][r] * scale + rb[r];
                accS[t][r] = v;
                rmax = fmaxf(rmax, v);
            }
        }
        rmax = fmaxf(rmax, __shfl_xor(rmax, 16, 64));
        rmax = fmaxf(rmax, __shfl_xor(rmax, 32, 64));
        float rsum = 0.0f;
        for (int t = 0; t < 16; ++t)
            for (int r = 0; r < 4; ++r) {
                float p = __expf(accS[t][r] - rmax);
                accS[t][r] = p;
                rsum += p;
            }
        rsum += __shfl_xor(rsum, 16, 64);
        rsum += __shfl_xor(rsum, 32, 64);
        float rinv = 1.0f / rsum;

        // P (pre-divided) -> LDS, b64 per t: token row l15, keys t*16+quad*4..+4
        for (int t = 0; t < 16; ++t) {
            ushort4v o;
            for (int r = 0; r < 4; ++r) o[r] = f2bf(accS[t][r] * rinv);
            *(ushort4v*)&psw[l15 * 264 + t * 16 + quad * 4] = o;
        }

        // PV: O[token][d] via A=P fragment (m=token), B=V^T fragment (n=d)
        floatx4 accO[2] = {};
        for (int kk = 0; kk < 8; ++kk) {
            short8 pf = *(short8*)&psw[l15 * 264 + kk * 32 + quad * 8];
            for (int tn = 0; tn < 2; ++tn) {
                short8 vf = *(short8*)&vts[(tn * 16 + l15) * 264 + kk * 32 + quad * 8];
                accO[tn] = __builtin_amdgcn_mfma_f32_16x16x32_bf16(pf, vf, accO[tn], 0, 0, 0);
            }
        }

        // epilogue: D[token=quad*4+r][d=tn*16+l15] overlay-store into q slice
        for (int tn = 0; tn < 2; ++tn)
            for (int r = 0; r < 4; ++r) {
                int n = mloc + quad * 4 + r;
                qp[n * HD + tn * 16 + l15] = f2bf(accO[tn][r]);
            }
    }
}

extern "C" void kernel_launch(void* const* d_in, const int* in_sizes, int n_in,
                              void* d_out, int out_size, void* d_ws, size_t ws_size,
                              hipStream_t stream)
{
    const void* x      = d_in[0];
    const void* qkv_w  = d_in[1];
    const void* q_bias = d_in[2];
    const void* v_bias = d_in[3];
    const void* lscale = d_in[4];
    const void* cpb_w1 = d_in[5];
    const void* cpb_b1 = d_in[6];
    const void* cpb_w2 = d_in[7];
    const void* proj_w = d_in[8];
    const void* proj_b = d_in[9];
    const void* rct    = d_in[10];
    const int*  rpi    = (const int*)d_in[11];

    char* ws = (char*)d_ws;
    ushort_t* qkv_ws  = (ushort_t*)ws;                          // 3*WSQ bf16 = 150,994,944 B
    float*    bt      = (float*)(ws + 150994944L);              // 961*12 f32
    float*    rpb     = (float*)(ws + 151060480L);              // 12*65536 f32 = 3,145,728 B
    int*      flag    = (int*)(ws + 154206208L);
    ushort_t* wqkv_b  = (ushort_t*)(ws + 154206464L);           // 1152*384 bf16 = 884,736 B
    ushort_t* wproj_b = (ushort_t*)(ws + 155091200L);           // 384*384 bf16 = 294,912 B
    ushort_t* xb      = (ushort_t*)d_out;                       // x in bf16 (50.3 MB scratch,
                                                                // consumed before final store)

    detect_kernel<<<1, 64, 0, stream>>>((const ushort_t*)x, flag);
    cvt_kernel<<<12288, 256, 0, stream>>>(x, xb, flag, 3145728L);      // x: 25,165,824 el
    cvt_kernel<<<216, 256, 0, stream>>>(qkv_w, wqkv_b, flag, 55296L);  // 442,368 el
    cvt_kernel<<<72, 256, 0, stream>>>(proj_w, wproj_b, flag, 18432L); // 147,456 el
    cpb_kernel<<<961, 512, 0, stream>>>(rct, cpb_w1, cpb_b1, cpb_w2, flag, bt);
    rpb_kernel<<<3072, 256, 0, stream>>>(rpi, bt, rpb);
    gemm_bt<0><<<dim3(9, 512), 256, 0, stream>>>(xb, wqkv_b, q_bias, v_bias, qkv_ws, flag);
    attn_kernel<<<3072, 128, 0, stream>>>(qkv_ws, lscale, rpb, flag);
    gemm_bt<1><<<dim3(3, 512), 256, 0, stream>>>(qkv_ws, wproj_b, proj_b, nullptr, d_out, flag);
}